// Round 1
// baseline (1722.722 us; speedup 1.0000x reference)
//
#include <hip/hip_runtime.h>
#include <hip/hip_bf16.h>

// Problem constants (hardcoded from setup_inputs):
// B=4, N=4096, C=256, h=8, d=32, H=W=L=16, M=512 (8x8x8), EPS=1e-5
#define SCALE_QK 0.17677669529663687f  // 32^-0.5

// ---------------------------------------------------------------------------
// prep: transpose weights (for coalesced GEMM reads) + zero ssq/sumv
// ---------------------------------------------------------------------------
__global__ __launch_bounds__(256) void prep_kernel(
    const float* __restrict__ pw, const float* __restrict__ kvw,
    const float* __restrict__ pjw,
    float* __restrict__ wtpw, float* __restrict__ wtkv, float* __restrict__ wtpj,
    float* __restrict__ ssq, float* __restrict__ sumv) {
  const int g = blockIdx.x * 256 + threadIdx.x;
  if (g < 65536) {
    const int c = g >> 8, o = g & 255;
    wtpw[g] = pw[o * 256 + c];
  } else if (g < 196608) {
    const int g2 = g - 65536;
    const int c = g2 >> 9, o = g2 & 511;
    wtkv[g2] = kvw[o * 256 + c];
  } else {
    const int g3 = g - 196608;
    const int c = g3 >> 8, o = g3 & 255;
    wtpj[g3] = pjw[o * 256 + c];
  }
  if (g < 32) ssq[g] = 0.0f;
  if (g >= 32 && g < 32 + 1024) sumv[g - 32] = 0.0f;
}

// ---------------------------------------------------------------------------
// depthwise conv3d (3x3x3, stride1, pad1) + BatchNorm (inference) -> qdw[B,N,C]
// one block per (b,n); thread = channel c (coalesced)
// ---------------------------------------------------------------------------
__global__ __launch_bounds__(256) void dwbn_kernel(
    const float* __restrict__ x, const float* __restrict__ w,
    const float* __restrict__ wb, const float* __restrict__ bg,
    const float* __restrict__ bb, const float* __restrict__ bm,
    const float* __restrict__ bv, float* __restrict__ outq) {
  const int blk = blockIdx.x;
  const int b = blk >> 12, n = blk & 4095;
  const int i0 = n >> 8, i1 = (n >> 4) & 15, i2 = n & 15;
  const int c = threadIdx.x;
  float acc = wb[c];
#pragma unroll
  for (int k0 = 0; k0 < 3; ++k0) {
    const int z = i0 + k0 - 1;
    if ((unsigned)z >= 16u) continue;
#pragma unroll
    for (int k1 = 0; k1 < 3; ++k1) {
      const int y = i1 + k1 - 1;
      if ((unsigned)y >= 16u) continue;
#pragma unroll
      for (int k2 = 0; k2 < 3; ++k2) {
        const int xx = i2 + k2 - 1;
        if ((unsigned)xx >= 16u) continue;
        acc = fmaf(w[c * 27 + (k0 * 3 + k1) * 3 + k2],
                   x[((b * 4096) + ((z * 16 + y) * 16 + xx)) * 256 + c], acc);
      }
    }
  }
  const float sc = bg[c] * rsqrtf(bv[c] + 1e-5f);
  outq[blk * 256 + c] = (acc - bm[c]) * sc + bb[c];
}

// ---------------------------------------------------------------------------
// strided depthwise conv3d (stride2) + LayerNorm over C -> xsln[B*M, C]
// one block per (b,m); thread = channel c
// ---------------------------------------------------------------------------
__global__ __launch_bounds__(256) void srln_kernel(
    const float* __restrict__ x, const float* __restrict__ w,
    const float* __restrict__ wb, const float* __restrict__ lg,
    const float* __restrict__ lb, float* __restrict__ outx) {
  const int blk = blockIdx.x;
  const int b = blk >> 9, m = blk & 511;
  const int o0 = m >> 6, o1 = (m >> 3) & 7, o2 = m & 7;
  const int c = threadIdx.x;
  float acc = wb[c];
#pragma unroll
  for (int k0 = 0; k0 < 3; ++k0) {
    const int z = o0 * 2 + k0 - 1;
    if ((unsigned)z >= 16u) continue;
#pragma unroll
    for (int k1 = 0; k1 < 3; ++k1) {
      const int y = o1 * 2 + k1 - 1;
      if ((unsigned)y >= 16u) continue;
#pragma unroll
      for (int k2 = 0; k2 < 3; ++k2) {
        const int xx = o2 * 2 + k2 - 1;
        if ((unsigned)xx >= 16u) continue;
        acc = fmaf(w[c * 27 + (k0 * 3 + k1) * 3 + k2],
                   x[((b * 4096) + ((z * 16 + y) * 16 + xx)) * 256 + c], acc);
      }
    }
  }
  // LayerNorm over 256 channels
  __shared__ float r1[4], r2[4];
  float s1 = acc, s2 = acc * acc;
#pragma unroll
  for (int off = 32; off >= 1; off >>= 1) {
    s1 += __shfl_xor(s1, off);
    s2 += __shfl_xor(s2, off);
  }
  const int t = threadIdx.x;
  if ((t & 63) == 0) { r1[t >> 6] = s1; r2[t >> 6] = s2; }
  __syncthreads();
  const float mu = (r1[0] + r1[1] + r1[2] + r1[3]) * (1.0f / 256.0f);
  const float ms = (r2[0] + r2[1] + r2[2] + r2[3]) * (1.0f / 256.0f);
  const float rs = rsqrtf(ms - mu * mu + 1e-5f);
  outx[blk * 256 + c] = (acc - mu) * rs * lg[c] + lb[c];
}

// ---------------------------------------------------------------------------
// GEMM: Out[row][c0+cc] = sum_k A[row][k] * Wt[k][c0+cc] (+bias)
// A is [R][256] row-major. 64 rows x 256 cols per block, 256 threads,
// thread computes 4 rows x 16 cols. MODE 1: instance-norm transform on A.
// ---------------------------------------------------------------------------
template <int MODE>
__global__ __launch_bounds__(256) void gemm_kernel(
    const float* __restrict__ A, const float* __restrict__ Wt,
    const float* __restrict__ bias, float* __restrict__ Out, const int ldW,
    const float* __restrict__ sumv, const float* __restrict__ rstd) {
  __shared__ float a_t[32][68];
  __shared__ float w_s[32][260];
  const int t = threadIdx.x;
  const int r0 = blockIdx.x * 64;
  const int c0 = blockIdx.y * 256;
  const int rt = t & 15, ct = t >> 4;
  const int bidx = r0 >> 12;
  const float invM = 1.0f / 512.0f;
  float acc[4][16];
#pragma unroll
  for (int rr = 0; rr < 4; ++rr)
#pragma unroll
    for (int cc = 0; cc < 16; ++cc) acc[rr][cc] = 0.0f;

  for (int k0 = 0; k0 < 256; k0 += 32) {
    {  // stage A^T
      const int kk = t & 31;
      int rl = t >> 5;
#pragma unroll
      for (int p = 0; p < 8; ++p, rl += 8) {
        float v = A[(r0 + rl) * 256 + k0 + kk];
        if (MODE == 1) {
          const int kg = k0 + kk;
          v = (v - invM * sumv[bidx * 256 + kg]) * rstd[bidx * 8 + (kg >> 5)];
        }
        a_t[kk][rl] = v;
      }
    }
    {  // stage W
      const int cq = (t & 63) * 4;
      int kk = t >> 6;
#pragma unroll
      for (int p = 0; p < 8; ++p, kk += 4) {
        const float4 v = *(const float4*)&Wt[(k0 + kk) * ldW + c0 + cq];
        *(float4*)&w_s[kk][cq] = v;
      }
    }
    __syncthreads();
#pragma unroll
    for (int kk = 0; kk < 32; ++kk) {
      const float4 a4 = *(const float4*)&a_t[kk][rt * 4];
      const float av[4] = {a4.x, a4.y, a4.z, a4.w};
      float4 w4[4];
#pragma unroll
      for (int q = 0; q < 4; ++q) w4[q] = *(const float4*)&w_s[kk][ct * 16 + q * 4];
#pragma unroll
      for (int rr = 0; rr < 4; ++rr) {
#pragma unroll
        for (int q = 0; q < 4; ++q) {
          acc[rr][q * 4 + 0] = fmaf(av[rr], w4[q].x, acc[rr][q * 4 + 0]);
          acc[rr][q * 4 + 1] = fmaf(av[rr], w4[q].y, acc[rr][q * 4 + 1]);
          acc[rr][q * 4 + 2] = fmaf(av[rr], w4[q].z, acc[rr][q * 4 + 2]);
          acc[rr][q * 4 + 3] = fmaf(av[rr], w4[q].w, acc[rr][q * 4 + 3]);
        }
      }
    }
    __syncthreads();
  }
  // epilogue
#pragma unroll
  for (int rr = 0; rr < 4; ++rr) {
    const int row = r0 + rt * 4 + rr;
#pragma unroll
    for (int q = 0; q < 4; ++q) {
      const int cc = c0 + ct * 16 + q * 4;
      float4 o;
      o.x = acc[rr][q * 4 + 0];
      o.y = acc[rr][q * 4 + 1];
      o.z = acc[rr][q * 4 + 2];
      o.w = acc[rr][q * 4 + 3];
      if (bias != nullptr) {
        o.x += bias[cc + 0]; o.y += bias[cc + 1];
        o.z += bias[cc + 2]; o.w += bias[cc + 3];
      }
      *(float4*)&Out[row * ldW + cc] = o;
    }
  }
}

// ---------------------------------------------------------------------------
// sumv[b][c] = sum_m v[b][m][c]  (v = kv cols 256..511); 32 blocks partial+atomic
// ---------------------------------------------------------------------------
__global__ __launch_bounds__(256) void sumv_kernel(const float* __restrict__ kvb,
                                                   float* __restrict__ sumv) {
  const int blk = blockIdx.x;  // b*8+grp
  const int b = blk >> 3, grp = blk & 7;
  const int c = threadIdx.x;
  float s = 0.0f;
  for (int mm = 0; mm < 64; ++mm) {
    const int m = grp * 64 + mm;
    s += kvb[((b * 512 + m) * 512) + 256 + c];
  }
  atomicAdd(&sumv[b * 256 + c], s);
}

__global__ void rstd_kernel(const float* __restrict__ ssq, float* __restrict__ rstd) {
  const int t = threadIdx.x;
  if (t < 32) {
    const float e2 = ssq[t] * (1.0f / (4096.0f * 512.0f));
    const float invM = 1.0f / 512.0f;
    rstd[t] = rsqrtf(e2 - invM * invM + 1e-5f);
  }
}

// ---------------------------------------------------------------------------
// Fused attention: per block = (b, 4 query rows). Computes per-head scores,
// 8x8 head mix + bias, softmax over M=512 (in registers), sum p^2 (atomic),
// and unnormalized P*V -> out_un[B,N,C].
// LDS: one 64KB score buffer, XOR-quad swizzled (key = row>>2) so that
// score writes (lane=m), mix reads (lane=m) and AV b128 reads (lane=head)
// are all bank-conflict free.
// ---------------------------------------------------------------------------
__device__ __forceinline__ int pidx(int row, int m) {
  return row * 512 + ((((m >> 2) ^ (row >> 2)) << 2) | (m & 3));
}

__global__ __launch_bounds__(256, 2) void attn_kernel(
    const float* __restrict__ qb, const float* __restrict__ kvb,
    const float* __restrict__ tw, const float* __restrict__ tb,
    float* __restrict__ ssq, float* __restrict__ out_un) {
  __shared__ float P[32 * 512];
  const int t = threadIdx.x;
  const int blk = blockIdx.x;
  const int b = blk >> 10;
  const int n0 = (blk & 1023) << 2;

  // ---------------- per-head raw scores (scaled) ----------------
  {
    const int j = t >> 5, mm = t & 31;
    float qr[4][32];
#pragma unroll
    for (int nn = 0; nn < 4; ++nn) {
      const float4* qp = (const float4*)&qb[((b * 4096 + n0 + nn) * 256) + j * 32];
#pragma unroll
      for (int qq = 0; qq < 8; ++qq) {
        const float4 v = qp[qq];
        qr[nn][qq * 4 + 0] = v.x * SCALE_QK;
        qr[nn][qq * 4 + 1] = v.y * SCALE_QK;
        qr[nn][qq * 4 + 2] = v.z * SCALE_QK;
        qr[nn][qq * 4 + 3] = v.w * SCALE_QK;
      }
    }
#pragma unroll 2
    for (int it = 0; it < 16; ++it) {
      const int m = mm + it * 32;
      const float4* kp = (const float4*)&kvb[((b * 512 + m) * 512) + j * 32];
      float a0 = 0.f, a1 = 0.f, a2 = 0.f, a3 = 0.f;
#pragma unroll
      for (int qq = 0; qq < 8; ++qq) {
        const float4 kq = kp[qq];
        a0 = fmaf(qr[0][qq * 4 + 0], kq.x, a0); a0 = fmaf(qr[0][qq * 4 + 1], kq.y, a0);
        a0 = fmaf(qr[0][qq * 4 + 2], kq.z, a0); a0 = fmaf(qr[0][qq * 4 + 3], kq.w, a0);
        a1 = fmaf(qr[1][qq * 4 + 0], kq.x, a1); a1 = fmaf(qr[1][qq * 4 + 1], kq.y, a1);
        a1 = fmaf(qr[1][qq * 4 + 2], kq.z, a1); a1 = fmaf(qr[1][qq * 4 + 3], kq.w, a1);
        a2 = fmaf(qr[2][qq * 4 + 0], kq.x, a2); a2 = fmaf(qr[2][qq * 4 + 1], kq.y, a2);
        a2 = fmaf(qr[2][qq * 4 + 2], kq.z, a2); a2 = fmaf(qr[2][qq * 4 + 3], kq.w, a2);
        a3 = fmaf(qr[3][qq * 4 + 0], kq.x, a3); a3 = fmaf(qr[3][qq * 4 + 1], kq.y, a3);
        a3 = fmaf(qr[3][qq * 4 + 2], kq.z, a3); a3 = fmaf(qr[3][qq * 4 + 3], kq.w, a3);
      }
      P[pidx(j * 4 + 0, m)] = a0;
      P[pidx(j * 4 + 1, m)] = a1;
      P[pidx(j * 4 + 2, m)] = a2;
      P[pidx(j * 4 + 3, m)] = a3;
    }
  }
  __syncthreads();

  // ---------------- head mix (wave w owns query row n=w) ----------------
  const int w = t >> 6, l = t & 63;
  float mixed[8][8];
  {
    float Wr[8][8];
#pragma unroll
    for (int i = 0; i < 8; ++i)
#pragma unroll
      for (int jj = 0; jj < 8; ++jj) Wr[i][jj] = tw[i * 8 + jj];
#pragma unroll
    for (int i = 0; i < 8; ++i) {
      const float bi = tb[i];
#pragma unroll
      for (int it = 0; it < 8; ++it) mixed[i][it] = bi;
    }
    for (int it = 0; it < 8; ++it) {
      const int m = l + it * 64;
#pragma unroll
      for (int jj = 0; jj < 8; ++jj) {
        const float r = P[pidx(jj * 4 + w, m)];
#pragma unroll
        for (int i = 0; i < 8; ++i) mixed[i][it] = fmaf(Wr[i][jj], r, mixed[i][it]);
      }
    }
  }
  // rows (i*4+w) are wave-private between mix and softmax: no barrier needed.

  // ---------------- softmax in registers + p^2 ----------------
#pragma unroll
  for (int i = 0; i < 8; ++i) {
    float mx = mixed[i][0];
#pragma unroll
    for (int it = 1; it < 8; ++it) mx = fmaxf(mx, mixed[i][it]);
#pragma unroll
    for (int off = 32; off >= 1; off >>= 1) mx = fmaxf(mx, __shfl_xor(mx, off));
    float s = 0.0f;
#pragma unroll
    for (int it = 0; it < 8; ++it) {
      const float e = __expf(mixed[i][it] - mx);
      mixed[i][it] = e;
      s += e;
    }
#pragma unroll
    for (int off = 32; off >= 1; off >>= 1) s += __shfl_xor(s, off);
    const float rinv = 1.0f / s;
    float sq = 0.0f;
#pragma unroll
    for (int it = 0; it < 8; ++it) {
      const float p = mixed[i][it] * rinv;
      sq = fmaf(p, p, sq);
      P[pidx(i * 4 + w, l + it * 64)] = p;
    }
#pragma unroll
    for (int off = 32; off >= 1; off >>= 1) sq += __shfl_xor(sq, off);
    if (l == 0) atomicAdd(&ssq[b * 8 + i], sq);
  }
  __syncthreads();

  // ---------------- P*V (wave w owns m in [w*128, w*128+128)) ----------------
  {
    const int iv = (t & 63) >> 3, ds = t & 7;
    const int mbase = w * 128;
    float acc[4][4];
#pragma unroll
    for (int nn = 0; nn < 4; ++nn)
#pragma unroll
      for (int e = 0; e < 4; ++e) acc[nn][e] = 0.0f;
    for (int mq = 0; mq < 32; ++mq) {
      const int m0 = mbase + mq * 4;
      float4 p4[4];
#pragma unroll
      for (int nn = 0; nn < 4; ++nn)
        p4[nn] = *(const float4*)&P[(iv * 4 + nn) * 512 + (((m0 >> 2) ^ iv) << 2)];
#pragma unroll
      for (int e = 0; e < 4; ++e) {
        const float4 v4 =
            *(const float4*)&kvb[((b * 512 + m0 + e) * 512) + 256 + iv * 32 + ds * 4];
#pragma unroll
        for (int nn = 0; nn < 4; ++nn) {
          const float p = (&p4[nn].x)[e];
          acc[nn][0] = fmaf(p, v4.x, acc[nn][0]);
          acc[nn][1] = fmaf(p, v4.y, acc[nn][1]);
          acc[nn][2] = fmaf(p, v4.z, acc[nn][2]);
          acc[nn][3] = fmaf(p, v4.w, acc[nn][3]);
        }
      }
    }
    __syncthreads();  // all P reads done before reuse as partial buffer
#pragma unroll
    for (int nn = 0; nn < 4; ++nn) {
      float4 o;
      o.x = acc[nn][0]; o.y = acc[nn][1]; o.z = acc[nn][2]; o.w = acc[nn][3];
      *(float4*)&P[w * 1024 + (iv * 4 + nn) * 32 + ds * 4] = o;
    }
  }
  __syncthreads();
  // cross-wave reduce of partials, write out_un
#pragma unroll
  for (int rep = 0; rep < 4; ++rep) {
    const int idx = rep * 256 + t;
    const float s = P[idx] + P[1024 + idx] + P[2048 + idx] + P[3072 + idx];
    const int row = idx >> 5, dd = idx & 31;
    const int iv = row >> 2, nn = row & 3;
    out_un[((b * 4096) + n0 + nn) * 256 + iv * 32 + dd] = s;
  }
}

// ---------------------------------------------------------------------------
extern "C" void kernel_launch(void* const* d_in, const int* in_sizes, int n_in,
                              void* d_out, int out_size, void* d_ws, size_t ws_size,
                              hipStream_t stream) {
  const float* x   = (const float*)d_in[0];
  const float* qdww= (const float*)d_in[1];
  const float* qdwb= (const float*)d_in[2];
  const float* bng = (const float*)d_in[3];
  const float* bnb = (const float*)d_in[4];
  const float* bnm = (const float*)d_in[5];
  const float* bnv = (const float*)d_in[6];
  const float* pw  = (const float*)d_in[7];
  const float* pwb = (const float*)d_in[8];
  const float* srw = (const float*)d_in[9];
  const float* srb = (const float*)d_in[10];
  const float* lng = (const float*)d_in[11];
  const float* lnb = (const float*)d_in[12];
  const float* kvw = (const float*)d_in[13];
  const float* tw  = (const float*)d_in[14];
  const float* tb  = (const float*)d_in[15];
  const float* pjw = (const float*)d_in[16];
  const float* pjb = (const float*)d_in[17];
  float* out = (float*)d_out;
  float* ws = (float*)d_ws;

  float* qdw   = ws + 0;          // 4,194,304
  float* qbuf  = ws + 4194304;    // 4,194,304
  float* xsln  = ws + 8388608;    //   524,288
  float* kvb   = ws + 8912896;    // 1,048,576
  float* wtpw  = ws + 9961472;    //    65,536
  float* wtkv  = ws + 10027008;   //   131,072
  float* wtpj  = ws + 10158080;   //    65,536
  float* sumvp = ws + 10223616;   //     1,024
  float* ssqp  = ws + 10224640;   //        32
  float* rstdp = ws + 10224672;   //        32

  prep_kernel<<<1024, 256, 0, stream>>>(pw, kvw, pjw, wtpw, wtkv, wtpj, ssqp, sumvp);
  dwbn_kernel<<<16384, 256, 0, stream>>>(x, qdww, qdwb, bng, bnb, bnm, bnv, qdw);
  gemm_kernel<0><<<dim3(256, 1), 256, 0, stream>>>(qdw, wtpw, pwb, qbuf, 256, nullptr, nullptr);
  srln_kernel<<<2048, 256, 0, stream>>>(x, srw, srb, lng, lnb, xsln);
  gemm_kernel<0><<<dim3(32, 2), 256, 0, stream>>>(xsln, wtkv, nullptr, kvb, 512, nullptr, nullptr);
  sumv_kernel<<<32, 256, 0, stream>>>(kvb, sumvp);
  attn_kernel<<<4096, 256, 0, stream>>>(qbuf, kvb, tw, tb, ssqp, out);
  rstd_kernel<<<1, 64, 0, stream>>>(ssqp, rstdp);
  gemm_kernel<1><<<dim3(256, 1), 256, 0, stream>>>(out, wtpj, pjb, out, 256, sumvp, rstdp);
}

// Round 4
// 640.059 us; speedup vs baseline: 2.6915x; 2.6915x over previous
//
#include <hip/hip_runtime.h>
#include <hip/hip_bf16.h>

// Problem constants (hardcoded from setup_inputs):
// B=4, N=4096, C=256, h=8, d=32, H=W=L=16, M=512 (8x8x8), EPS=1e-5
#define SCALE_QK 0.17677669529663687f  // 32^-0.5

// ---------------------------------------------------------------------------
// prep: transpose weights (for coalesced GEMM reads) + zero ssq/sumv
// ---------------------------------------------------------------------------
__global__ __launch_bounds__(256) void prep_kernel(
    const float* __restrict__ pw, const float* __restrict__ kvw,
    const float* __restrict__ pjw,
    float* __restrict__ wtpw, float* __restrict__ wtkv, float* __restrict__ wtpj,
    float* __restrict__ ssq, float* __restrict__ sumv) {
  const int g = blockIdx.x * 256 + threadIdx.x;
  if (g < 65536) {
    const int c = g >> 8, o = g & 255;
    wtpw[g] = pw[o * 256 + c];
  } else if (g < 196608) {
    const int g2 = g - 65536;
    const int c = g2 >> 9, o = g2 & 511;
    wtkv[g2] = kvw[o * 256 + c];
  } else {
    const int g3 = g - 196608;
    const int c = g3 >> 8, o = g3 & 255;
    wtpj[g3] = pjw[o * 256 + c];
  }
  if (g < 512) ssq[g] = 0.0f;                      // 16-way spread x 32
  if (g >= 512 && g < 512 + 1024) sumv[g - 512] = 0.0f;
}

// ---------------------------------------------------------------------------
// depthwise conv3d (3x3x3, stride1, pad1) + BatchNorm (inference) -> qdw[B,N,C]
// ---------------------------------------------------------------------------
__global__ __launch_bounds__(256) void dwbn_kernel(
    const float* __restrict__ x, const float* __restrict__ w,
    const float* __restrict__ wb, const float* __restrict__ bg,
    const float* __restrict__ bb, const float* __restrict__ bm,
    const float* __restrict__ bv, float* __restrict__ outq) {
  const int blk = blockIdx.x;
  const int b = blk >> 12, n = blk & 4095;
  const int i0 = n >> 8, i1 = (n >> 4) & 15, i2 = n & 15;
  const int c = threadIdx.x;
  float acc = wb[c];
#pragma unroll
  for (int k0 = 0; k0 < 3; ++k0) {
    const int z = i0 + k0 - 1;
    if ((unsigned)z >= 16u) continue;
#pragma unroll
    for (int k1 = 0; k1 < 3; ++k1) {
      const int y = i1 + k1 - 1;
      if ((unsigned)y >= 16u) continue;
#pragma unroll
      for (int k2 = 0; k2 < 3; ++k2) {
        const int xx = i2 + k2 - 1;
        if ((unsigned)xx >= 16u) continue;
        acc = fmaf(w[c * 27 + (k0 * 3 + k1) * 3 + k2],
                   x[((b * 4096) + ((z * 16 + y) * 16 + xx)) * 256 + c], acc);
      }
    }
  }
  const float sc = bg[c] * rsqrtf(bv[c] + 1e-5f);
  outq[blk * 256 + c] = (acc - bm[c]) * sc + bb[c];
}

// ---------------------------------------------------------------------------
// strided depthwise conv3d (stride2) + LayerNorm over C -> xsln[B*M, C]
// ---------------------------------------------------------------------------
__global__ __launch_bounds__(256) void srln_kernel(
    const float* __restrict__ x, const float* __restrict__ w,
    const float* __restrict__ wb, const float* __restrict__ lg,
    const float* __restrict__ lb, float* __restrict__ outx) {
  const int blk = blockIdx.x;
  const int b = blk >> 9, m = blk & 511;
  const int o0 = m >> 6, o1 = (m >> 3) & 7, o2 = m & 7;
  const int c = threadIdx.x;
  float acc = wb[c];
#pragma unroll
  for (int k0 = 0; k0 < 3; ++k0) {
    const int z = o0 * 2 + k0 - 1;
    if ((unsigned)z >= 16u) continue;
#pragma unroll
    for (int k1 = 0; k1 < 3; ++k1) {
      const int y = o1 * 2 + k1 - 1;
      if ((unsigned)y >= 16u) continue;
#pragma unroll
      for (int k2 = 0; k2 < 3; ++k2) {
        const int xx = o2 * 2 + k2 - 1;
        if ((unsigned)xx >= 16u) continue;
        acc = fmaf(w[c * 27 + (k0 * 3 + k1) * 3 + k2],
                   x[((b * 4096) + ((z * 16 + y) * 16 + xx)) * 256 + c], acc);
      }
    }
  }
  __shared__ float r1[4], r2[4];
  float s1 = acc, s2 = acc * acc;
#pragma unroll
  for (int off = 32; off >= 1; off >>= 1) {
    s1 += __shfl_xor(s1, off);
    s2 += __shfl_xor(s2, off);
  }
  const int t = threadIdx.x;
  if ((t & 63) == 0) { r1[t >> 6] = s1; r2[t >> 6] = s2; }
  __syncthreads();
  const float mu = (r1[0] + r1[1] + r1[2] + r1[3]) * (1.0f / 256.0f);
  const float ms = (r2[0] + r2[1] + r2[2] + r2[3]) * (1.0f / 256.0f);
  const float rs = rsqrtf(ms - mu * mu + 1e-5f);
  outx[blk * 256 + c] = (acc - mu) * rs * lg[c] + lb[c];
}

// ---------------------------------------------------------------------------
// GEMM: Out[row][c0+cc] = sum_k A[row][k] * Wt[k][c0+cc] (+bias)
// MODE 1: deferred-instance-norm transform on A while staging.
// ---------------------------------------------------------------------------
template <int MODE>
__global__ __launch_bounds__(256) void gemm_kernel(
    const float* __restrict__ A, const float* __restrict__ Wt,
    const float* __restrict__ bias, float* __restrict__ Out, const int ldW,
    const float* __restrict__ sumv, const float* __restrict__ rstd) {
  __shared__ float a_t[32][68];
  __shared__ float w_s[32][260];
  const int t = threadIdx.x;
  const int r0 = blockIdx.x * 64;
  const int c0 = blockIdx.y * 256;
  const int rt = t & 15, ct = t >> 4;
  const int bidx = r0 >> 12;
  const float invM = 1.0f / 512.0f;
  float acc[4][16];
#pragma unroll
  for (int rr = 0; rr < 4; ++rr)
#pragma unroll
    for (int cc = 0; cc < 16; ++cc) acc[rr][cc] = 0.0f;

  for (int k0 = 0; k0 < 256; k0 += 32) {
    {  // stage A^T
      const int kk = t & 31;
      int rl = t >> 5;
#pragma unroll
      for (int p = 0; p < 8; ++p, rl += 8) {
        float v = A[(r0 + rl) * 256 + k0 + kk];
        if (MODE == 1) {
          const int kg = k0 + kk;
          v = (v - invM * sumv[bidx * 256 + kg]) * rstd[bidx * 8 + (kg >> 5)];
        }
        a_t[kk][rl] = v;
      }
    }
    {  // stage W
      const int cq = (t & 63) * 4;
      int kk = t >> 6;
#pragma unroll
      for (int p = 0; p < 8; ++p, kk += 4) {
        const float4 v = *(const float4*)&Wt[(k0 + kk) * ldW + c0 + cq];
        *(float4*)&w_s[kk][cq] = v;
      }
    }
    __syncthreads();
#pragma unroll
    for (int kk = 0; kk < 32; ++kk) {
      const float4 a4 = *(const float4*)&a_t[kk][rt * 4];
      const float av[4] = {a4.x, a4.y, a4.z, a4.w};
      float4 w4[4];
#pragma unroll
      for (int q = 0; q < 4; ++q) w4[q] = *(const float4*)&w_s[kk][ct * 16 + q * 4];
#pragma unroll
      for (int rr = 0; rr < 4; ++rr) {
#pragma unroll
        for (int q = 0; q < 4; ++q) {
          acc[rr][q * 4 + 0] = fmaf(av[rr], w4[q].x, acc[rr][q * 4 + 0]);
          acc[rr][q * 4 + 1] = fmaf(av[rr], w4[q].y, acc[rr][q * 4 + 1]);
          acc[rr][q * 4 + 2] = fmaf(av[rr], w4[q].z, acc[rr][q * 4 + 2]);
          acc[rr][q * 4 + 3] = fmaf(av[rr], w4[q].w, acc[rr][q * 4 + 3]);
        }
      }
    }
    __syncthreads();
  }
#pragma unroll
  for (int rr = 0; rr < 4; ++rr) {
    const int row = r0 + rt * 4 + rr;
#pragma unroll
    for (int q = 0; q < 4; ++q) {
      const int cc = c0 + ct * 16 + q * 4;
      float4 o;
      o.x = acc[rr][q * 4 + 0];
      o.y = acc[rr][q * 4 + 1];
      o.z = acc[rr][q * 4 + 2];
      o.w = acc[rr][q * 4 + 3];
      if (bias != nullptr) {
        o.x += bias[cc + 0]; o.y += bias[cc + 1];
        o.z += bias[cc + 2]; o.w += bias[cc + 3];
      }
      *(float4*)&Out[row * ldW + cc] = o;
    }
  }
}

// ---------------------------------------------------------------------------
// kt: K^T per batch -> ktb[b][k<256][m<512] (coalesced QK reads). LDS tiled.
// ---------------------------------------------------------------------------
__global__ __launch_bounds__(256) void kt_kernel(const float* __restrict__ kvb,
                                                 float* __restrict__ ktb) {
  __shared__ float tile[32][33];
  const int blk = blockIdx.x;  // b(4) x mt(16) x kt8(8)
  const int b = blk >> 7, mt = (blk >> 3) & 15, k8 = blk & 7;
  const int m0 = mt * 32, k0 = k8 * 32;
  const int t = threadIdx.x;
  {
    const int ml = t >> 3, kl = (t & 7) * 4;
    const float4 v = *(const float4*)&kvb[((b * 512 + m0 + ml) * 512) + k0 + kl];
    tile[ml][kl + 0] = v.x; tile[ml][kl + 1] = v.y;
    tile[ml][kl + 2] = v.z; tile[ml][kl + 3] = v.w;
  }
  __syncthreads();
  {
    const int kl = t >> 3, ml = (t & 7) * 4;
    float4 o;
    o.x = tile[ml + 0][kl]; o.y = tile[ml + 1][kl];
    o.z = tile[ml + 2][kl]; o.w = tile[ml + 3][kl];
    *(float4*)&ktb[((b * 256 + k0 + kl) * 512) + m0 + ml] = o;
  }
}

// ---------------------------------------------------------------------------
// sumv[b][c] = sum_m v[b][m][c]
// ---------------------------------------------------------------------------
__global__ __launch_bounds__(256) void sumv_kernel(const float* __restrict__ kvb,
                                                   float* __restrict__ sumv) {
  const int blk = blockIdx.x;
  const int b = blk >> 3, grp = blk & 7;
  const int c = threadIdx.x;
  float s = 0.0f;
  for (int mm = 0; mm < 64; ++mm) {
    const int m = grp * 64 + mm;
    s += kvb[((b * 512 + m) * 512) + 256 + c];
  }
  atomicAdd(&sumv[b * 256 + c], s);
}

__global__ void rstd_kernel(const float* __restrict__ ssq, float* __restrict__ rstd) {
  const int t = threadIdx.x;
  if (t < 32) {
    float s = 0.0f;
#pragma unroll
    for (int sp = 0; sp < 16; ++sp) s += ssq[sp * 32 + t];
    const float e2 = s * (1.0f / (4096.0f * 512.0f));
    const float invM = 1.0f / 512.0f;
    rstd[t] = rsqrtf(e2 - invM * invM + 1e-5f);
  }
}

// ---------------------------------------------------------------------------
// Fused attention v2: block = (b, 4 query rows), wave w owns row n0+w.
// QK from pre-transposed KT (coalesced, lane = 4 m's), raw scores + 8x8 head
// mix + softmax fully in registers (wave-wide shfl reduce over m=512).
// p -> LDS (XOR-quad swizzle) for the PV phase (unchanged from v1).
// ssq: in-block LDS reduce -> 8 spread atomics per block.
// ---------------------------------------------------------------------------
__global__ __launch_bounds__(256, 2) void attn_kernel(
    const float* __restrict__ qb, const float* __restrict__ ktb,
    const float* __restrict__ kvb, const float* __restrict__ tw,
    const float* __restrict__ tb, float* __restrict__ ssq,
    float* __restrict__ out_un) {
  __shared__ float P[32 * 512];
  __shared__ float Qs[4 * 256];
  __shared__ float sq_lds[4][8];
  const int t = threadIdx.x;
  const int blk = blockIdx.x;
  const int b = blk >> 10;
  const int n0 = (blk & 1023) << 2;

  {  // stage Q rows, scaled
    const int row = t >> 6, col = (t & 63) << 2;
    const float4 v = *(const float4*)&qb[((b * 4096 + n0 + row) * 256) + col];
    float4 s;
    s.x = v.x * SCALE_QK; s.y = v.y * SCALE_QK;
    s.z = v.z * SCALE_QK; s.w = v.w * SCALE_QK;
    *(float4*)&Qs[row * 256 + col] = s;
  }
  __syncthreads();

  const int w = t >> 6, l = t & 63;

  // ---------------- QK: raw[j][c*4+e] = score head j at m=c*256+l*4+e -------
  float raw[8][8];
#pragma unroll
  for (int j = 0; j < 8; ++j)
#pragma unroll
    for (int e = 0; e < 8; ++e) raw[j][e] = 0.0f;

  const float* ktbase = &ktb[(b * 256) << 9];
#pragma unroll
  for (int j = 0; j < 8; ++j) {
#pragma unroll 4
    for (int kq = 0; kq < 8; ++kq) {
      const float4 q4 = *(const float4*)&Qs[w * 256 + j * 32 + kq * 4];
#pragma unroll
      for (int e = 0; e < 4; ++e) {
        const int k = j * 32 + kq * 4 + e;
        const float4 k0 = *(const float4*)&ktbase[(k << 9) + (l << 2)];
        const float4 k1 = *(const float4*)&ktbase[(k << 9) + 256 + (l << 2)];
        const float qv = (&q4.x)[e];
        raw[j][0] = fmaf(qv, k0.x, raw[j][0]);
        raw[j][1] = fmaf(qv, k0.y, raw[j][1]);
        raw[j][2] = fmaf(qv, k0.z, raw[j][2]);
        raw[j][3] = fmaf(qv, k0.w, raw[j][3]);
        raw[j][4] = fmaf(qv, k1.x, raw[j][4]);
        raw[j][5] = fmaf(qv, k1.y, raw[j][5]);
        raw[j][6] = fmaf(qv, k1.z, raw[j][6]);
        raw[j][7] = fmaf(qv, k1.w, raw[j][7]);
      }
    }
  }

  // ---------------- 8x8 head mix (+bias), in place ----------------
  {
    float Wr[8][8], tbr[8];
#pragma unroll
    for (int i = 0; i < 8; ++i) {
      tbr[i] = tb[i];
#pragma unroll
      for (int jj = 0; jj < 8; ++jj) Wr[i][jj] = tw[i * 8 + jj];
    }
#pragma unroll
    for (int e = 0; e < 8; ++e) {
      float tmp[8];
#pragma unroll
      for (int i = 0; i < 8; ++i) tmp[i] = tbr[i];
#pragma unroll
      for (int jj = 0; jj < 8; ++jj) {
        const float r = raw[jj][e];
#pragma unroll
        for (int i = 0; i < 8; ++i) tmp[i] = fmaf(Wr[i][jj], r, tmp[i]);
      }
#pragma unroll
      for (int i = 0; i < 8; ++i) raw[i][e] = tmp[i];
    }
  }

  // ---------------- softmax over m=512 (in-lane 8 + 64-lane shfl) -----------
#pragma unroll
  for (int i = 0; i < 8; ++i) {
    float mx = raw[i][0];
#pragma unroll
    for (int e = 1; e < 8; ++e) mx = fmaxf(mx, raw[i][e]);
#pragma unroll
    for (int off = 32; off >= 1; off >>= 1) mx = fmaxf(mx, __shfl_xor(mx, off));
    float s = 0.0f;
#pragma unroll
    for (int e = 0; e < 8; ++e) {
      const float ev = __expf(raw[i][e] - mx);
      raw[i][e] = ev;
      s += ev;
    }
#pragma unroll
    for (int off = 32; off >= 1; off >>= 1) s += __shfl_xor(s, off);
    const float rinv = 1.0f / s;
    float sq = 0.0f;
#pragma unroll
    for (int c = 0; c < 2; ++c) {
      float4 pv;
#pragma unroll
      for (int e = 0; e < 4; ++e) {
        const float p = raw[i][c * 4 + e] * rinv;
        (&pv.x)[e] = p;
        sq = fmaf(p, p, sq);
      }
      // pidx swizzle: row=i*4+w (row>>2==i), quad=(c*64+l)^i
      *(float4*)&P[(i * 4 + w) * 512 + (((c * 64 + l) ^ i) << 2)] = pv;
    }
#pragma unroll
    for (int off = 32; off >= 1; off >>= 1) sq += __shfl_xor(sq, off);
    if (l == 0) sq_lds[w][i] = sq;
  }
  __syncthreads();

  // ---------------- ssq: one spread atomic per (block, head) ----------------
  if (t < 8) {
    const float s8 = sq_lds[0][t] + sq_lds[1][t] + sq_lds[2][t] + sq_lds[3][t];
    atomicAdd(&ssq[(blk & 15) * 32 + b * 8 + t], s8);
  }

  // ---------------- P*V (wave w owns m in [w*128, w*128+128)) ---------------
  {
    const int iv = (t & 63) >> 3, ds = t & 7;
    const int mbase = w * 128;
    float acc[4][4];
#pragma unroll
    for (int nn = 0; nn < 4; ++nn)
#pragma unroll
      for (int e = 0; e < 4; ++e) acc[nn][e] = 0.0f;
    for (int mq = 0; mq < 32; ++mq) {
      const int m0 = mbase + mq * 4;
      float4 p4[4];
#pragma unroll
      for (int nn = 0; nn < 4; ++nn)
        p4[nn] = *(const float4*)&P[(iv * 4 + nn) * 512 + (((m0 >> 2) ^ iv) << 2)];
#pragma unroll
      for (int e = 0; e < 4; ++e) {
        const float4 v4 =
            *(const float4*)&kvb[((b * 512 + m0 + e) * 512) + 256 + iv * 32 + ds * 4];
#pragma unroll
        for (int nn = 0; nn < 4; ++nn) {
          const float p = (&p4[nn].x)[e];
          acc[nn][0] = fmaf(p, v4.x, acc[nn][0]);
          acc[nn][1] = fmaf(p, v4.y, acc[nn][1]);
          acc[nn][2] = fmaf(p, v4.z, acc[nn][2]);
          acc[nn][3] = fmaf(p, v4.w, acc[nn][3]);
        }
      }
    }
    __syncthreads();  // all P reads done before reuse as partial buffer
#pragma unroll
    for (int nn = 0; nn < 4; ++nn) {
      float4 o;
      o.x = acc[nn][0]; o.y = acc[nn][1]; o.z = acc[nn][2]; o.w = acc[nn][3];
      *(float4*)&P[w * 1024 + (iv * 4 + nn) * 32 + ds * 4] = o;
    }
  }
  __syncthreads();
#pragma unroll
  for (int rep = 0; rep < 4; ++rep) {
    const int idx = rep * 256 + t;
    const float s = P[idx] + P[1024 + idx] + P[2048 + idx] + P[3072 + idx];
    const int row = idx >> 5, dd = idx & 31;
    const int iv = row >> 2, nn = row & 3;
    out_un[((b * 4096) + n0 + nn) * 256 + iv * 32 + dd] = s;
  }
}

// ---------------------------------------------------------------------------
extern "C" void kernel_launch(void* const* d_in, const int* in_sizes, int n_in,
                              void* d_out, int out_size, void* d_ws, size_t ws_size,
                              hipStream_t stream) {
  const float* x   = (const float*)d_in[0];
  const float* qdww= (const float*)d_in[1];
  const float* qdwb= (const float*)d_in[2];
  const float* bng = (const float*)d_in[3];
  const float* bnb = (const float*)d_in[4];
  const float* bnm = (const float*)d_in[5];
  const float* bnv = (const float*)d_in[6];
  const float* pw  = (const float*)d_in[7];
  const float* pwb = (const float*)d_in[8];
  const float* srw = (const float*)d_in[9];
  const float* srb = (const float*)d_in[10];
  const float* lng = (const float*)d_in[11];
  const float* lnb = (const float*)d_in[12];
  const float* kvw = (const float*)d_in[13];
  const float* tw  = (const float*)d_in[14];
  const float* tb  = (const float*)d_in[15];
  const float* pjw = (const float*)d_in[16];
  const float* pjb = (const float*)d_in[17];
  float* out = (float*)d_out;
  float* ws = (float*)d_ws;

  float* qdw   = ws + 0;          // 4,194,304
  float* qbuf  = ws + 4194304;    // 4,194,304
  float* xsln  = ws + 8388608;    //   524,288
  float* kvb   = ws + 8912896;    // 1,048,576
  float* ktb   = ws + 9961472;    //   524,288
  float* wtpw  = ws + 10485760;   //    65,536
  float* wtkv  = ws + 10551296;   //   131,072
  float* wtpj  = ws + 10682368;   //    65,536
  float* sumvp = ws + 10747904;   //     1,024
  float* ssqp  = ws + 10748928;   //       512
  float* rstdp = ws + 10749440;   //        32

  prep_kernel<<<1024, 256, 0, stream>>>(pw, kvw, pjw, wtpw, wtkv, wtpj, ssqp, sumvp);
  dwbn_kernel<<<16384, 256, 0, stream>>>(x, qdww, qdwb, bng, bnb, bnm, bnv, qdw);
  gemm_kernel<0><<<dim3(256, 1), 256, 0, stream>>>(qdw, wtpw, pwb, qbuf, 256, nullptr, nullptr);
  srln_kernel<<<2048, 256, 0, stream>>>(x, srw, srb, lng, lnb, xsln);
  gemm_kernel<0><<<dim3(32, 2), 256, 0, stream>>>(xsln, wtkv, nullptr, kvb, 512, nullptr, nullptr);
  kt_kernel<<<512, 256, 0, stream>>>(kvb, ktb);
  sumv_kernel<<<32, 256, 0, stream>>>(kvb, sumvp);
  attn_kernel<<<4096, 256, 0, stream>>>(qbuf, ktb, kvb, tw, tb, ssqp, out);
  rstd_kernel<<<1, 64, 0, stream>>>(ssqp, rstdp);
  gemm_kernel<1><<<dim3(256, 1), 256, 0, stream>>>(out, wtpj, pjb, out, 256, sumvp, rstdp);
}